// Round 3
// baseline (3289.034 us; speedup 1.0000x reference)
//
#include <hip/hip_runtime.h>
#include <hip/hip_bf16.h>
#include <stdint.h>

// Problem constants
#define B_ 8
#define H_ 512
#define F_ 256
#define P_ 12
#define M_ 4096          // B*H
#define K1_ 16384        // N*F = 64*256
#define J_ 1024          // 4*F

typedef __attribute__((ext_vector_type(8))) short short8;
typedef __attribute__((ext_vector_type(4))) float floatx4;

union FragU { uint4 u; short8 s; };
union U2   { unsigned long long v[2]; uint4 u; short8 s; };

// Workspace layout (bytes)
// NOTE: HX/EP alias the head of W1H — W1H is dead after k_gemm1, and k_init
// runs after k_gemm1 / before k_encoder (stream-ordered), so no conflict.
#define OFF_HX    ((size_t)0)          //      8,192  h exchange buffer (1024 ull)
#define OFF_EP    ((size_t)8192)       //        512  epoch flags (8 x 64B)
#define OFF_W1H   ((size_t)0)          //  8,388,608  W1 swizzled bf16 hi
#define OFF_W1L   ((size_t)8388608)    //  8,388,608  W1 swizzled bf16 lo
#define OFF_WHSW  ((size_t)16777216)   //    524,288  Wh swizzled bf16
#define OFF_ENC   ((size_t)17301504)   //  4,194,304  encoder states fp32 [8][512][256]
#define OFF_C     ((size_t)21495808)   //      8,192  final c state [8][256]
#define OFF_XSUM  ((size_t)21504000)   //  4,194,304  xs transposed [256][4096]
#define OFF_XPRE  ((size_t)25698304)   // 16,777,216  Xpre [4096][1024]
#define OFF_P1    ((size_t)42475520)   // 33,554,432  split-K partials [8][256][4096]
// total ~76.0 MB

__device__ __forceinline__ unsigned short f2bf(float f) {
  uint32_t u = __float_as_uint(f);
  u += 0x7fffu + ((u >> 16) & 1u);
  return (unsigned short)(u >> 16);
}
__device__ __forceinline__ float bf2f(unsigned short h) {
  return __uint_as_float(((uint32_t)h) << 16);
}
__device__ __forceinline__ float sigm(float x) { return 1.f / (1.f + __expf(-x)); }
__device__ __forceinline__ float tanh_(float x) {
  float ax = fabsf(x);
  float e  = __expf(-2.f * ax);
  float t  = (1.f - e) / (1.f + e);
  return x < 0.f ? -t : t;
}

// ---------------------------------------------------------------------------
// Prep: W1 -> bf16 hi/lo in MFMA A-fragment swizzled layout.
__global__ void k_prep_w1(const float* __restrict__ W1,
                          uint4* __restrict__ hi, uint4* __restrict__ lo) {
  int idx  = blockIdx.x * 1024 + threadIdx.x;     // 0..524287
  int lane = idx & 63;
  int kt   = (idx >> 6) & 511;
  int nt   = idx >> 15;                            // 0..15
  int n    = nt * 16 + (lane & 15);
  int kb   = kt * 32 + ((lane >> 4) << 3);
  unsigned short h8[8], l8[8];
#pragma unroll
  for (int j = 0; j < 8; ++j) {
    float v = W1[(size_t)(kb + j) * 256 + n];
    unsigned short hh = f2bf(v);
    h8[j] = hh;
    l8[j] = f2bf(v - bf2f(hh));
  }
  uint4 uh, ul;
  uh.x = (uint32_t)h8[0] | ((uint32_t)h8[1] << 16);
  uh.y = (uint32_t)h8[2] | ((uint32_t)h8[3] << 16);
  uh.z = (uint32_t)h8[4] | ((uint32_t)h8[5] << 16);
  uh.w = (uint32_t)h8[6] | ((uint32_t)h8[7] << 16);
  ul.x = (uint32_t)l8[0] | ((uint32_t)l8[1] << 16);
  ul.y = (uint32_t)l8[2] | ((uint32_t)l8[3] << 16);
  ul.z = (uint32_t)l8[4] | ((uint32_t)l8[5] << 16);
  ul.w = (uint32_t)l8[6] | ((uint32_t)l8[7] << 16);
  hi[idx] = uh;
  lo[idx] = ul;
}

// Wh -> bf16 swizzled A-fragments. Fragment (zt, kt): m = z col, k = h index.
__global__ void k_prep_wh(const float* __restrict__ Wh, uint4* __restrict__ sw) {
  int idx  = blockIdx.x * 1024 + threadIdx.x;     // 0..32767
  int lane = idx & 63;
  int kt   = (idx >> 6) & 7;
  int zt   = idx >> 9;                             // 0..63
  int col  = zt * 16 + (lane & 15);
  int kb   = kt * 32 + ((lane >> 4) << 3);
  unsigned short h8[8];
#pragma unroll
  for (int j = 0; j < 8; ++j) h8[j] = f2bf(Wh[(size_t)(kb + j) * 1024 + col]);
  uint4 u;
  u.x = (uint32_t)h8[0] | ((uint32_t)h8[1] << 16);
  u.y = (uint32_t)h8[2] | ((uint32_t)h8[3] << 16);
  u.z = (uint32_t)h8[4] | ((uint32_t)h8[5] << 16);
  u.w = (uint32_t)h8[6] | ((uint32_t)h8[7] << 16);
  sw[idx] = u;
}

// ---------------------------------------------------------------------------
// GEMM1 split-K (unchanged)
__global__ __launch_bounds__(1024)
void k_gemm1(const float* __restrict__ x, const uint4* __restrict__ w1h,
             const uint4* __restrict__ w1l, float* __restrict__ P1) {
  __shared__ __align__(16) unsigned short xh[128 * 40];
  __shared__ __align__(16) unsigned short xl[128 * 40];
  int bm = blockIdx.x >> 3, kc = blockIdx.x & 7;
  int m0 = bm * 128, kcbase = kc * 2048;
  int tid = threadIdx.x, wave = tid >> 6, lane = tid & 63;
  int quad = lane >> 4, l15 = lane & 15;
  int srow = tid >> 3, skch = tid & 7;
  floatx4 acc[8];
#pragma unroll
  for (int mt = 0; mt < 8; ++mt) acc[mt] = (floatx4)(0.f);

  for (int it = 0; it < 64; ++it) {
    int kb = kcbase + it * 32;
    const float4 xv = *(const float4*)(x + (size_t)(m0 + srow) * K1_ + kb + skch * 4);
    unsigned short h0 = f2bf(xv.x), h1 = f2bf(xv.y), h2 = f2bf(xv.z), h3 = f2bf(xv.w);
    unsigned short g0 = f2bf(xv.x - bf2f(h0)), g1 = f2bf(xv.y - bf2f(h1));
    unsigned short g2 = f2bf(xv.z - bf2f(h2)), g3 = f2bf(xv.w - bf2f(h3));
    uint2 ph, pl;
    ph.x = (uint32_t)h0 | ((uint32_t)h1 << 16); ph.y = (uint32_t)h2 | ((uint32_t)h3 << 16);
    pl.x = (uint32_t)g0 | ((uint32_t)g1 << 16); pl.y = (uint32_t)g2 | ((uint32_t)g3 << 16);
    *(uint2*)&xh[srow * 40 + skch * 4] = ph;
    *(uint2*)&xl[srow * 40 + skch * 4] = pl;
    __syncthreads();

    size_t aoff = (size_t)(wave * 512 + kc * 64 + it) * 64 + lane;
    FragU ah; ah.u = w1h[aoff];
    FragU al; al.u = w1l[aoff];
#pragma unroll
    for (int mt = 0; mt < 8; ++mt) {
      FragU bh, bl;
      bh.u = *(const uint4*)&xh[(mt * 16 + l15) * 40 + quad * 8];
      bl.u = *(const uint4*)&xl[(mt * 16 + l15) * 40 + quad * 8];
      acc[mt] = __builtin_amdgcn_mfma_f32_16x16x32_bf16(ah.s, bh.s, acc[mt], 0, 0, 0);
      acc[mt] = __builtin_amdgcn_mfma_f32_16x16x32_bf16(ah.s, bl.s, acc[mt], 0, 0, 0);
      acc[mt] = __builtin_amdgcn_mfma_f32_16x16x32_bf16(al.s, bh.s, acc[mt], 0, 0, 0);
    }
    __syncthreads();
  }
  int nbase = wave * 16 + quad * 4;
#pragma unroll
  for (int mt = 0; mt < 8; ++mt) {
    int m = m0 + mt * 16 + l15;
#pragma unroll
    for (int r = 0; r < 4; ++r)
      P1[(size_t)(kc * 256 + nbase + r) * M_ + m] = acc[mt][r];
  }
}

// Sum split-K partials + b1 -> xsum[k][m]
__global__ void k_reduce(const float* __restrict__ P1, const float* __restrict__ b1,
                         float* __restrict__ xsum) {
  int idx = blockIdx.x * 1024 + threadIdx.x;       // 1,048,576
  int k = idx >> 12, m = idx & 4095;
  float s = b1[k];
#pragma unroll
  for (int kc = 0; kc < 8; ++kc) s += P1[(size_t)(kc * 256 + k) * M_ + m];
  xsum[(size_t)k * M_ + m] = s;
}

// GEMM2 (fp32 VALU, unchanged)
__global__ __launch_bounds__(256)
void k_gemm2(const float* __restrict__ xsum, const float* __restrict__ Wx,
             const float* __restrict__ bz, float* __restrict__ Xpre) {
  int m0 = blockIdx.x * 16;
  int j = threadIdx.x;
  float acc0[16], acc1[16], acc2[16], acc3[16];
  float bb0 = bz[j], bb1 = bz[256 + j], bb2 = bz[512 + j], bb3 = bz[768 + j];
#pragma unroll
  for (int mm = 0; mm < 16; ++mm) { acc0[mm] = bb0; acc1[mm] = bb1; acc2[mm] = bb2; acc3[mm] = bb3; }
  for (int k = 0; k < 256; ++k) {
    float w0 = Wx[(size_t)k * 1024 + j];
    float w1 = Wx[(size_t)k * 1024 + 256 + j];
    float w2 = Wx[(size_t)k * 1024 + 512 + j];
    float w3 = Wx[(size_t)k * 1024 + 768 + j];
#pragma unroll
    for (int mm = 0; mm < 16; ++mm) {
      float xv = xsum[(size_t)k * M_ + m0 + mm];
      acc0[mm] += xv * w0; acc1[mm] += xv * w1; acc2[mm] += xv * w2; acc3[mm] += xv * w3;
    }
  }
#pragma unroll
  for (int mm = 0; mm < 16; ++mm) {
    float* o = Xpre + (size_t)(m0 + mm) * 1024;
    o[j] = acc0[mm]; o[256 + j] = acc1[mm]; o[512 + j] = acc2[mm]; o[768 + j] = acc3[mm];
  }
}

// ---------------------------------------------------------------------------
// init for encoder exchange: h0 = 0, epoch = 1 (h input for step 0 ready)
__global__ void k_init(unsigned long long* __restrict__ hx8,
                       unsigned int* __restrict__ ep) {
  int tid = threadIdx.x;
#pragma unroll
  for (int i = 0; i < 4; ++i) hx8[tid * 4 + i] = 0ull;
  if (tid < 8) ep[tid * 16] = 1u;
}

// ---------------------------------------------------------------------------
// Encoder v3: 8 cooperating blocks; batches in MFMA B columns
// (cols 0..7 = h_hi per batch, 8..15 = h_lo). Block j owns z rows
// [g*256 + 32j, +32) of every gate g -> produces h[32j..32j+32) for all
// batches. Weights: 16 frags/wave, fully register-resident (64 VGPRs).
// h exchanged per step via agent-scope (cross-XCD coherent) atomics.
__global__ __launch_bounds__(256, 1)
void k_encoder(const uint4* __restrict__ whsw, const float* __restrict__ xpre,
               float* __restrict__ enc, float* __restrict__ cws,
               unsigned long long* __restrict__ hx8, unsigned int* __restrict__ ep) {
  __shared__ float zbuf[4 * 16 * 33];                    // [gate][col][krow+pad]
  __shared__ __align__(8) unsigned short hloc[16 * 32];  // [col][k'] bf16
  int j = blockIdx.x, tid = threadIdx.x;
  int g = tid >> 6, lane = tid & 63;                     // wave g = gate g
  int quad = lane >> 4, l15 = lane & 15;
  int b = tid >> 5, k = tid & 31;                        // gate-phase identity

  // register-resident weights: zt pair {g*16+2j, g*16+2j+1}
  uint4 wfr[16];
#pragma unroll
  for (int zl = 0; zl < 2; ++zl)
#pragma unroll
    for (int kt = 0; kt < 8; ++kt)
      wfr[zl * 8 + kt] = whsw[(size_t)(((g * 16 + 2 * j + zl) * 8 + kt) * 64 + lane)];

  float creg = 0.f;
  const float* xp_base = xpre + (size_t)(l15 & 7) * 512 * 1024 + g * 256 + j * 32 + quad * 4;
  floatx4 xq[2];
  xq[0] = (floatx4)(0.f); xq[1] = (floatx4)(0.f);
  if (l15 < 8) {
    xq[0] = *(const floatx4*)(xp_base + 0);
    xq[1] = *(const floatx4*)(xp_base + 16);
  }

  for (int t = 0; t < 512; ++t) {
    // wait for all 8 blocks' h (epoch t+1)
    if (tid < 8) {
      while (__hip_atomic_load(&ep[tid * 16], __ATOMIC_ACQUIRE,
                               __HIP_MEMORY_SCOPE_AGENT) < (unsigned)(t + 1)) {
        __builtin_amdgcn_s_sleep(1);
      }
    }
    __syncthreads();

    // B fragments via coherent loads (bypass stale per-XCD caches)
    U2 bf[8];
#pragma unroll
    for (int kt = 0; kt < 8; ++kt) {
      bf[kt].v[0] = __hip_atomic_load(&hx8[(kt * 64 + lane) * 2 + 0],
                                      __ATOMIC_RELAXED, __HIP_MEMORY_SCOPE_AGENT);
      bf[kt].v[1] = __hip_atomic_load(&hx8[(kt * 64 + lane) * 2 + 1],
                                      __ATOMIC_RELAXED, __HIP_MEMORY_SCOPE_AGENT);
    }

    // prefetch next step's Xpre slice (independent)
    floatx4 nxq[2];
    nxq[0] = (floatx4)(0.f); nxq[1] = (floatx4)(0.f);
    if (t < 511 && l15 < 8) {
      nxq[0] = *(const floatx4*)(xp_base + (size_t)(t + 1) * 1024);
      nxq[1] = *(const floatx4*)(xp_base + (size_t)(t + 1) * 1024 + 16);
    }

    // MFMA: 2 zt tiles x 8 kt; acc init = Xpre (hi cols) / 0 (lo cols)
#pragma unroll
    for (int zl = 0; zl < 2; ++zl) {
      floatx4 acc = xq[zl];
#pragma unroll
      for (int kt = 0; kt < 8; ++kt) {
        FragU a; a.u = wfr[zl * 8 + kt];
        FragU bb; bb.u = bf[kt].u;
        acc = __builtin_amdgcn_mfma_f32_16x16x32_bf16(a.s, bb.s, acc, 0, 0, 0);
      }
#pragma unroll
      for (int r = 0; r < 4; ++r)
        zbuf[g * 528 + l15 * 33 + zl * 16 + quad * 4 + r] = acc[r];
    }
    __syncthreads();

    // gates: thread (b,k) -> h[b][j*32+k]; z = hi-col + lo-col
    float zi = zbuf[0 * 528 + b * 33 + k] + zbuf[0 * 528 + (b + 8) * 33 + k];
    float zf = zbuf[1 * 528 + b * 33 + k] + zbuf[1 * 528 + (b + 8) * 33 + k];
    float zg = zbuf[2 * 528 + b * 33 + k] + zbuf[2 * 528 + (b + 8) * 33 + k];
    float zo = zbuf[3 * 528 + b * 33 + k] + zbuf[3 * 528 + (b + 8) * 33 + k];
    float ig = sigm(zi), fg = sigm(zf), gg = tanh_(zg), og = sigm(zo);
    float cn = fg * creg + ig * gg;
    creg = cn;
    float hn = og * tanh_(cn);
    enc[((size_t)b * 512 + t) * 256 + j * 32 + k] = hn;
    unsigned short hh = f2bf(hn);
    hloc[b * 32 + k] = hh;
    hloc[(b + 8) * 32 + k] = f2bf(hn - bf2f(hh));
    __syncthreads();

    // publish h slice (frag-layout chunk row kt=j) + epoch flag
    if (t < 511) {
      if (tid < 128) {
        int q_ = tid >> 5, c_ = (tid >> 1) & 15, h_ = tid & 1;
        unsigned long long v =
            ((const unsigned long long*)hloc)[c_ * 8 + q_ * 2 + h_];
        __hip_atomic_store(&hx8[j * 128 + tid], v,
                           __ATOMIC_RELAXED, __HIP_MEMORY_SCOPE_AGENT);
      }
      __syncthreads();   // drains stores (vmcnt(0) before barrier)
      if (tid == 0) {
        __threadfence();
        __hip_atomic_store(&ep[j * 16], (unsigned)(t + 2),
                           __ATOMIC_RELEASE, __HIP_MEMORY_SCOPE_AGENT);
      }
    }
    xq[0] = nxq[0]; xq[1] = nxq[1];
  }
  cws[b * 256 + j * 32 + k] = creg;
}

// ---------------------------------------------------------------------------
// Decoder (unchanged)
__global__ __launch_bounds__(1024)
void k_decoder(const float* __restrict__ enc, const float* __restrict__ cws,
               const float* __restrict__ Wx, const float* __restrict__ Wh,
               const float* __restrict__ bz, const float* __restrict__ Wa,
               const float* __restrict__ ba, const float* __restrict__ W2,
               const float* __restrict__ b2, float* __restrict__ out) {
  __shared__ float h[256], c[256], q[256], ctx[256];
  __shared__ float sc[512];
  __shared__ float zb[1024];
  __shared__ float smx[2];
  int b = blockIdx.x, tid = threadIdx.x;
  int wave = tid >> 6, lane = tid & 63;
  const float* encb = enc + (size_t)b * 512 * 256;
  if (tid < 256) { h[tid] = encb[(size_t)511 * 256 + tid]; c[tid] = cws[b * 256 + tid]; }
  __syncthreads();

  for (int p = 0; p < 12; ++p) {
    {
      int j = tid & 255, ks = tid >> 8;
      float s = 0.f;
      for (int kk = 0; kk < 64; ++kk) {
        int k = ks * 64 + kk;
        s += h[k] * Wa[(size_t)k * 256 + j];
      }
      zb[tid] = s;
    }
    __syncthreads();
    if (tid < 256) q[tid] = ba[tid] + zb[tid] + zb[256 + tid] + zb[512 + tid] + zb[768 + tid];
    __syncthreads();
    {
      float4 qv = *(const float4*)&q[lane * 4];
      for (int r = 0; r < 32; ++r) {
        int hh = wave * 32 + r;
        const float4 ev = *(const float4*)(encb + (size_t)hh * 256 + lane * 4);
        float s = ev.x * qv.x + ev.y * qv.y + ev.z * qv.z + ev.w * qv.w;
#pragma unroll
        for (int off = 32; off >= 1; off >>= 1) s += __shfl_xor(s, off, 64);
        if (lane == 0) sc[hh] = s;
      }
    }
    __syncthreads();
    if (tid < 64) {
      float m = -3.4e38f;
      for (int r = 0; r < 8; ++r) m = fmaxf(m, sc[tid * 8 + r]);
#pragma unroll
      for (int off = 32; off >= 1; off >>= 1) m = fmaxf(m, __shfl_xor(m, off, 64));
      if (tid == 0) smx[0] = m;
    }
    __syncthreads();
    if (tid < 512) sc[tid] = __expf(sc[tid] - smx[0]);
    __syncthreads();
    if (tid < 64) {
      float s = 0.f;
      for (int r = 0; r < 8; ++r) s += sc[tid * 8 + r];
#pragma unroll
      for (int off = 32; off >= 1; off >>= 1) s += __shfl_xor(s, off, 64);
      if (tid == 0) smx[1] = 1.f / s;
    }
    __syncthreads();
    {
      int k = tid & 255, hs = tid >> 8;
      float s = 0.f;
      for (int r = 0; r < 128; ++r) {
        int hh = hs * 128 + r;
        s += sc[hh] * encb[(size_t)hh * 256 + k];
      }
      zb[tid] = s;
    }
    __syncthreads();
    if (tid < 256) ctx[tid] = (zb[tid] + zb[256 + tid] + zb[512 + tid] + zb[768 + tid]) * smx[1];
    __syncthreads();
    {
      float s = bz[tid];
      for (int k = 0; k < 256; ++k) {
        s += ctx[k] * Wx[(size_t)k * 1024 + tid] + h[k] * Wh[(size_t)k * 1024 + tid];
      }
      zb[tid] = s;
    }
    __syncthreads();
    if (tid < 256) {
      float zi = zb[tid], zf = zb[256 + tid], zg = zb[512 + tid], zo = zb[768 + tid];
      float ig = sigm(zi), fg = sigm(zf), gg = tanh_(zg), og = sigm(zo);
      float cn = fg * c[tid] + ig * gg;
      c[tid] = cn;
      h[tid] = og * tanh_(cn);
    }
    __syncthreads();
    if (tid < 64) {
      float s = b2[tid];
      for (int f = 0; f < 256; ++f) s += h[f] * W2[(size_t)f * 64 + tid];
      out[((size_t)b * 12 + p) * 64 + tid] = s;
    }
    __syncthreads();
  }
}

// ---------------------------------------------------------------------------
extern "C" void kernel_launch(void* const* d_in, const int* in_sizes, int n_in,
                              void* d_out, int out_size, void* d_ws, size_t ws_size,
                              hipStream_t stream) {
  const float* x  = (const float*)d_in[0];
  const float* W1 = (const float*)d_in[1];
  const float* b1 = (const float*)d_in[2];
  const float* Wx = (const float*)d_in[3];
  const float* Wh = (const float*)d_in[4];
  const float* bz = (const float*)d_in[5];
  const float* Wa = (const float*)d_in[6];
  const float* ba = (const float*)d_in[7];
  const float* W2 = (const float*)d_in[8];
  const float* b2 = (const float*)d_in[9];

  char* ws = (char*)d_ws;
  uint4* w1h  = (uint4*)(ws + OFF_W1H);
  uint4* w1l  = (uint4*)(ws + OFF_W1L);
  uint4* whsw = (uint4*)(ws + OFF_WHSW);
  float* enc  = (float*)(ws + OFF_ENC);
  float* cws  = (float*)(ws + OFF_C);
  float* xsum = (float*)(ws + OFF_XSUM);
  float* xpre = (float*)(ws + OFF_XPRE);
  float* p1   = (float*)(ws + OFF_P1);
  unsigned long long* hx8 = (unsigned long long*)(ws + OFF_HX);
  unsigned int* ep        = (unsigned int*)(ws + OFF_EP);

  k_prep_w1<<<dim3(512), dim3(1024), 0, stream>>>(W1, w1h, w1l);
  k_prep_wh<<<dim3(32), dim3(1024), 0, stream>>>(Wh, whsw);
  k_gemm1<<<dim3(256), dim3(1024), 0, stream>>>(x, w1h, w1l, p1);
  k_reduce<<<dim3(1024), dim3(1024), 0, stream>>>(p1, b1, xsum);
  k_gemm2<<<dim3(256), dim3(256), 0, stream>>>(xsum, Wx, bz, xpre);
  k_init<<<dim3(1), dim3(256), 0, stream>>>(hx8, ep);
  k_encoder<<<dim3(8), dim3(256), 0, stream>>>(whsw, xpre, enc, cws, hx8, ep);
  k_decoder<<<dim3(8), dim3(1024), 0, stream>>>(enc, cws, Wx, Wh, bz, Wa, ba, W2, b2,
                                                (float*)d_out);
}